// Round 3
// baseline (422.852 us; speedup 1.0000x reference)
//
#include <hip/hip_runtime.h>

// SSIM3D fused, plane-march v3.
// Grid: z-tiles(3) x y-tiles(24) x (x-chunks(6) * batch(2)) = 864 blocks -> all co-resident
// (LDS 36.9KB -> 4 blocks/CU; 864 <= 1024). Block = 256 threads.
// Block owns output slab y0..y0+7, z0..z0+61, x-chunk of 31; marches 37 input planes.
// Software pipeline: global loads for plane xi+1 issued right after plane xi's
// registers are written to LDS -> HBM latency overlaps z/y/accum compute.

#define DIMS 192
#define OD   186
#define ZCH  62      // output tile along z
#define XCH  31      // output chunk along x (186 = 6*31)
#define NP   37      // input planes per x-chunk = XCH + 6
#define YT   8       // output rows per block
#define YIN  14      // input rows = YT + 6

// LDS layout (floats)
#define ST_OFF 0      // stage[2][14][73]  (row pad 73 -> 2-way-free z-conv reads)
#define ST_F   1022   // 14*73
#define ST_J   73
#define ZP_OFF 2048   // zplane[5][14][64], k swizzled by +17*j
#define ZP_F   896    // 14*64
#define YP_OFF 6528   // yplane[5][8][64]
#define YP_F   512    // 8*64
#define LDS_N  9088

#define STAGE_N (2 * YIN * 68)   // 1904 elements per plane

__global__ __launch_bounds__(256, 4)
void ssim3d_kernel(const float* __restrict__ X, const float* __restrict__ Y,
                   double* __restrict__ acc_out) {
    __shared__ float lds[LDS_N];
    __shared__ float wsum[4];
    const int tid = threadIdx.x;

    // 1D Gaussian softmax weights (separable); wave-uniform via readfirstlane.
    float w[7];
    {
        float s = 0.f;
        #pragma unroll
        for (int t = 0; t < 7; ++t) {
            float d = (float)t - 3.0f;
            w[t] = expf(-d * d / 4.5f);   // sigma=1.5 -> 2*sigma^2=4.5
            s += w[t];
        }
        #pragma unroll
        for (int t = 0; t < 7; ++t)
            w[t] = __uint_as_float(__builtin_amdgcn_readfirstlane(__float_as_uint(w[t] / s)));
    }

    const int z0 = blockIdx.x * ZCH;
    const int y0 = blockIdx.y * YT;
    const int cx = blockIdx.z % 6;
    const int n  = blockIdx.z / 6;
    const int x0 = cx * XCH;

    const float* Xb = X + (size_t)n * (DIMS * DIMS * DIMS);
    const float* Yb = Y + (size_t)n * (DIMS * DIMS * DIMS);

    // Precompute per-thread stage coordinates (loop-invariant).
    int st_lds[8];            // LDS float index for slot
    size_t st_goff[8];        // global offset within a plane (field base + row + z)
    #pragma unroll
    for (int it = 0; it < 8; ++it) {
        int idx = tid + it * 256;
        if (idx < STAGE_N) {
            int fld = idx / (YIN * 68);
            int r   = idx - fld * (YIN * 68);
            int j   = r / 68;
            int z   = r - j * 68;
            int gy  = min(y0 + j, DIMS - 1);
            st_lds[it]  = ST_OFF + fld * ST_F + j * ST_J + z;
            st_goff[it] = (size_t)gy * DIMS + z0 + z;   // field chosen at load
        } else {
            st_lds[it] = -1; st_goff[it] = 0;
        }
    }

    // x-conv ring accumulators: acc[q][2f+pt]
    float acc[7][10];
    #pragma unroll
    for (int q = 0; q < 7; ++q)
        #pragma unroll
        for (int m = 0; m < 10; ++m) acc[q][m] = 0.f;

    const int aj = tid >> 6;                 // 0..3 (wave-uniform)
    const int ak = tid & 63;
    const bool v1 = (ak < ZCH) && (y0 + aj < OD);
    const bool v2 = (ak < ZCH) && (y0 + aj + 4 < OD);

    const int zj = tid >> 4;                 // 0..15 (valid < 14)
    const int zs = tid & 15;

    float lsum = 0.f;
    const float c1 = 1e-4f, c2 = 9e-4f;

    float pf[8];
    // ---- prologue: load plane 0 ----
    {
        const size_t pbase = (size_t)x0 * (DIMS * DIMS);
        #pragma unroll
        for (int it = 0; it < 8; ++it) {
            int idx = tid + it * 256;
            if (st_lds[it] >= 0) {
                const float* src = (idx >= YIN * 68) ? Yb : Xb;
                pf[it] = src[pbase + st_goff[it]];
            }
        }
    }

    for (int xi = 0; xi < NP; ++xi) {
        // ---- write staged registers to LDS (waits on in-flight loads) ----
        #pragma unroll
        for (int it = 0; it < 8; ++it)
            if (st_lds[it] >= 0) lds[st_lds[it]] = pf[it];

        // ---- issue loads for next plane (overlap with compute below) ----
        if (xi + 1 < NP) {
            const size_t pbase = (size_t)(x0 + xi + 1) * (DIMS * DIMS);
            #pragma unroll
            for (int it = 0; it < 8; ++it) {
                int idx = tid + it * 256;
                if (st_lds[it] >= 0) {
                    const float* src = (idx >= YIN * 68) ? Yb : Xb;
                    pf[it] = src[pbase + st_goff[it]];
                }
            }
        }
        __syncthreads();

        // ---- z-conv: 5 fields, sliding window, 4 outputs per thread ----
        if (zj < YIN) {
            float xv[10], yv[10];
            const float* px = &lds[ST_OFF + zj * ST_J + zs * 4];
            const float* py = px + ST_F;
            #pragma unroll
            for (int t = 0; t < 10; ++t) { xv[t] = px[t]; yv[t] = py[t]; }
            const int swb = ZP_OFF + zj * 64;
            #pragma unroll
            for (int o = 0; o < 4; ++o) {
                int k = zs * 4 + o;
                float a0 = 0.f, a1 = 0.f, a2 = 0.f, a3 = 0.f, a4 = 0.f;
                #pragma unroll
                for (int t = 0; t < 7; ++t) {
                    float xx = xv[o + t], yy = yv[o + t], wt = w[t];
                    a0 += wt * xx;
                    a1 += wt * yy;
                    a2 += wt * (xx * xx);
                    a3 += wt * (yy * yy);
                    a4 += wt * (xx * yy);
                }
                if (k < ZCH) {
                    int b = swb + ((k + 17 * zj) & 63);
                    lds[b]            = a0;
                    lds[b + ZP_F]     = a1;
                    lds[b + 2 * ZP_F] = a2;
                    lds[b + 3 * ZP_F] = a3;
                    lds[b + 4 * ZP_F] = a4;
                }
            }
        }
        __syncthreads();

        // ---- y-conv: task = (field f, column k); 310 tasks ----
        #pragma unroll
        for (int pass = 0; pass < 2; ++pass) {
            int idx = tid + pass * 256;
            if (idx < 5 * ZCH) {
                int f = idx / ZCH;
                int k = idx - f * ZCH;
                float v[YIN];
                const int fb = ZP_OFF + f * ZP_F;
                #pragma unroll
                for (int jj = 0; jj < YIN; ++jj)
                    v[jj] = lds[fb + jj * 64 + ((k + 17 * jj) & 63)];
                const int ob = YP_OFF + f * YP_F + k;
                #pragma unroll
                for (int j = 0; j < YT; ++j) {
                    float a = 0.f;
                    #pragma unroll
                    for (int t = 0; t < 7; ++t) a += w[t] * v[j + t];
                    lds[ob + j * 64] = a;
                }
            }
        }
        __syncthreads();

        // ---- accumulate into x-conv ring; slot q gets w[6-q] ----
        float vv[10];
        #pragma unroll
        for (int f = 0; f < 5; ++f) {
            vv[2 * f]     = lds[YP_OFF + f * YP_F + aj * 64 + ak];
            vv[2 * f + 1] = lds[YP_OFF + f * YP_F + (aj + 4) * 64 + ak];
        }
        #pragma unroll
        for (int q = 0; q < 7; ++q) {
            float wq = w[6 - q];
            #pragma unroll
            for (int m = 0; m < 10; ++m) acc[q][m] += wq * vv[m];
        }

        // ---- slot 0 complete: SSIM for output plane o = xi-6 ----
        if (xi >= 6) {
            #pragma unroll
            for (int pt = 0; pt < 2; ++pt) {
                bool valid = pt ? v2 : v1;
                if (valid) {
                    float mu1 = acc[0][0 + pt], mu2 = acc[0][2 + pt];
                    float ex2 = acc[0][4 + pt], ey2 = acc[0][6 + pt], exy = acc[0][8 + pt];
                    float mu11 = mu1 * mu1, mu22 = mu2 * mu2, mu12 = mu1 * mu2;
                    float s1 = ex2 - mu11, s2 = ey2 - mu22, s12 = exy - mu12;
                    float num = (2.f * mu12 + c1) * (2.f * s12 + c2);
                    float den = (mu11 + mu22 + c1) * ((s1 + s2) + c2);
                    lsum += num / den;
                }
            }
        }

        // ---- shift ring ----
        #pragma unroll
        for (int q = 0; q < 6; ++q)
            #pragma unroll
            for (int m = 0; m < 10; ++m) acc[q][m] = acc[q + 1][m];
        #pragma unroll
        for (int m = 0; m < 10; ++m) acc[6][m] = 0.f;
        // next iteration's ST write is safe: all threads passed the y-conv barrier,
        // z-conv ST reads are two barriers back.
    }

    // ---- block reduction ----
    #pragma unroll
    for (int off = 32; off > 0; off >>= 1) lsum += __shfl_down(lsum, off, 64);
    if ((tid & 63) == 0) wsum[tid >> 6] = lsum;
    __syncthreads();
    if (tid == 0)
        atomicAdd(acc_out, (double)(wsum[0] + wsum[1] + wsum[2] + wsum[3]));
}

__global__ void ssim3d_finalize(const double* __restrict__ acc, float* __restrict__ out) {
    out[0] = (float)(acc[0] / 12869712.0);   // 2 * 186^3
}

extern "C" void kernel_launch(void* const* d_in, const int* in_sizes, int n_in,
                              void* d_out, int out_size, void* d_ws, size_t ws_size,
                              hipStream_t stream) {
    (void)in_sizes; (void)n_in; (void)out_size; (void)ws_size;
    const float* x = (const float*)d_in[0];
    const float* y = (const float*)d_in[1];
    float* out = (float*)d_out;
    double* acc = (double*)d_ws;
    hipMemsetAsync(d_ws, 0, sizeof(double), stream);
    dim3 grid(3, 24, 12);   // z-tiles, y-tiles, x-chunks(6)*batch(2)
    ssim3d_kernel<<<grid, 256, 0, stream>>>(x, y, acc);
    ssim3d_finalize<<<1, 1, 0, stream>>>(acc, out);
}

// Round 4
// 237.764 us; speedup vs baseline: 1.7785x; 1.7785x over previous
//
#include <hip/hip_runtime.h>
#include <utility>

// SSIM3D fused v4: no stage phase (direct global->reg z-windows, prefetched),
// 2 barriers/plane, unroll-by-7 march (compile-time ring slots, no shifts),
// conflict-free transposed LDS layouts, balanced y-phase.
// Grid: 3 z-tiles x 24 y-tiles x (7 x-chunks * 2 batch) = 1008 blocks.

#define DIMS 192
#define OD   186
#define VOL  (DIMS * DIMS * DIMS)
#define ZCH  62      // z outputs per block (3*62 = 186)
#define XCH  27      // x outputs per chunk (7*27 = 189 >= 186, last chunk clipped)
#define NCHX 7
#define NP   (XCH + 6)   // 33 input planes
#define YT   8
#define YIN  14

// LDS layouts (floats):
//  zp[f][k][j]: f*930 + k*15 + j   (pitch 15: z-writes & y-reads 2-way free)
//  yp[f][k][j]: f*576 + k*9  + j   (pitch 9: all accesses 2-way free; k padded to 64)
#define ZP_P   15
#define ZP_F   (ZCH * ZP_P)          // 930
#define YP_F   576                   // 64*9
#define YP_OFF (5 * ZP_F)            // 4650
#define LDS_N  (YP_OFF + 5 * YP_F)   // 7530 floats = 30.1 KB -> 4 blocks/CU

__global__ __launch_bounds__(256, 4)
void ssim3d_kernel(const float* __restrict__ X, const float* __restrict__ Y,
                   double* __restrict__ acc_out) {
    __shared__ float lds[LDS_N];
    __shared__ float wsum[4];
    const int tid = threadIdx.x;

    // 1D Gaussian softmax weights, wave-uniform (SGPR).
    float w[7];
    {
        float s = 0.f;
        #pragma unroll
        for (int t = 0; t < 7; ++t) {
            float d = (float)t - 3.0f;
            w[t] = expf(-d * d / 4.5f);
            s += w[t];
        }
        #pragma unroll
        for (int t = 0; t < 7; ++t)
            w[t] = __uint_as_float(__builtin_amdgcn_readfirstlane(__float_as_uint(w[t] / s)));
    }

    const int z0 = blockIdx.x * ZCH;
    const int y0 = blockIdx.y * YT;
    const int cx = blockIdx.z % NCHX;
    const int n  = blockIdx.z / NCHX;
    const int x0 = cx * XCH;

    const float* Xb = X + (size_t)n * VOL;
    const float* Yb = Y + (size_t)n * VOL;

    // z-phase mapping: thread (zj, zs) -> row zj, z-cols zc..zc+9 (4 outputs)
    const int zj = tid >> 4;                 // 0..15 (active < 14)
    const int zs = tid & 15;
    const bool zact = (zj < YIN);
    const int zc = z0 + zs * 4;
    const int gy = min(y0 + zj, DIMS - 1);
    const unsigned rowoff = (unsigned)gy * DIMS + (unsigned)zc;
    const bool ztail = (zc + 9 > DIMS - 1);  // only z0=124, zs=15

    // y-phase mapping: 310 tasks split evenly across 4 waves (77/78 each)
    const int wv = tid >> 6;
    const int ln = tid & 63;
    const int ybase = (310 * wv) >> 2;
    const int ycnt  = ((310 * (wv + 1)) >> 2) - ybase;

    // accum mapping: thread owns points (aj, ak) and (aj+4, ak)
    const int aj = wv;
    const int ak = ln;
    const bool v1 = (ak < ZCH) && (y0 + aj < OD);
    const bool v2 = (ak < ZCH) && (y0 + aj + 4 < OD);
    const int xmax = OD + 6 - x0;            // xi < xmax -> output o = x0+xi-6 valid

    float acc[7][10];
    #pragma unroll
    for (int q = 0; q < 7; ++q)
        #pragma unroll
        for (int m = 0; m < 10; ++m) acc[q][m] = 0.f;

    float lsum = 0.f;
    const float c1 = 1e-4f, c2 = 9e-4f;

    float pfx[10], pfy[10];

    auto loadX = [&](int xi) {
        if (!zact) return;
        int gx = min(x0 + xi, DIMS - 1);
        const float* p = Xb + (size_t)gx * (DIMS * DIMS) + rowoff;
        #pragma unroll
        for (int t = 0; t < 4; ++t) {
            float2 a = *(const float2*)(p + 2 * t);
            pfx[2 * t] = a.x; pfx[2 * t + 1] = a.y;
        }
        if (!ztail) {
            float2 a = *(const float2*)(p + 8);
            pfx[8] = a.x; pfx[9] = a.y;
        } else { pfx[8] = 0.f; pfx[9] = 0.f; }
    };
    auto loadY = [&](int xi) {
        if (!zact) return;
        int gx = min(x0 + xi, DIMS - 1);
        const float* p = Yb + (size_t)gx * (DIMS * DIMS) + rowoff;
        #pragma unroll
        for (int t = 0; t < 4; ++t) {
            float2 a = *(const float2*)(p + 2 * t);
            pfy[2 * t] = a.x; pfy[2 * t + 1] = a.y;
        }
        if (!ztail) {
            float2 a = *(const float2*)(p + 8);
            pfy[8] = a.x; pfy[9] = a.y;
        } else { pfy[8] = 0.f; pfy[9] = 0.f; }
    };

    auto ssim_pt = [&](float mu1, float mu2, float ex2, float ey2, float exy) {
        float mu11 = mu1 * mu1, mu22 = mu2 * mu2, mu12 = mu1 * mu2;
        float num = (2.f * mu12 + c1) * (2.f * (exy - mu12) + c2);
        float den = (mu11 + mu22 + c1) * ((ex2 - mu11) + (ey2 - mu22) + c2);
        lsum += num * __builtin_amdgcn_rcpf(den);
    };

    auto body = [&](int xi, auto ucell) {
        constexpr int U = decltype(ucell)::value;   // U == xi % 7

        // ---- Phase A: z-conv from registers -> zp ----
        if (zact) {
            #pragma unroll
            for (int o = 0; o < 4; ++o) {
                float a0 = 0.f, a1 = 0.f, a2 = 0.f, a3 = 0.f, a4 = 0.f;
                #pragma unroll
                for (int t = 0; t < 7; ++t) {
                    float xx = pfx[o + t], yy = pfy[o + t], wt = w[t];
                    a0 += wt * xx;
                    a1 += wt * yy;
                    a2 += wt * (xx * xx);
                    a3 += wt * (yy * yy);
                    a4 += wt * (xx * yy);
                }
                int k = zs * 4 + o;
                if (k < ZCH) {
                    int b = k * ZP_P + zj;
                    lds[b]            = a0;
                    lds[b + ZP_F]     = a1;
                    lds[b + 2 * ZP_F] = a2;
                    lds[b + 3 * ZP_F] = a3;
                    lds[b + 4 * ZP_F] = a4;
                }
            }
        }
        if (xi + 1 < NP) loadX(xi + 1);   // prefetch X-field (WAR-safe, in-order issue)
        __syncthreads();

        // ---- Phase B: y-conv zp -> yp (balanced across waves) ----
        #pragma unroll
        for (int p2 = 0; p2 < 2; ++p2) {
            int rel = p2 * 64 + ln;
            if (rel < ycnt) {
                int t = ybase + rel;
                int f = t / ZCH;
                int k = t - f * ZCH;
                const float* src = &lds[f * ZP_F + k * ZP_P];
                float v[YIN];
                #pragma unroll
                for (int jj = 0; jj < YIN; ++jj) v[jj] = src[jj];
                float* dst = &lds[YP_OFF + f * YP_F + k * 9];
                #pragma unroll
                for (int j = 0; j < YT; ++j) {
                    float a = 0.f;
                    #pragma unroll
                    for (int tt = 0; tt < 7; ++tt) a += w[tt] * v[j + tt];
                    dst[j] = a;
                }
            }
        }
        if (xi + 1 < NP) loadY(xi + 1);   // prefetch Y-field
        __syncthreads();

        // ---- Phase C: ring accumulate (compile-time slots) + SSIM ----
        float vv[10];
        #pragma unroll
        for (int f = 0; f < 5; ++f) {
            vv[2 * f]     = lds[YP_OFF + f * YP_F + ak * 9 + aj];
            vv[2 * f + 1] = lds[YP_OFF + f * YP_F + ak * 9 + aj + 4];
        }
        #pragma unroll
        for (int d = 0; d < 7; ++d) {
            float wq = w[d];
            #pragma unroll
            for (int m = 0; m < 10; ++m)
                acc[(U + 7 - d) % 7][m] += wq * vv[m];   // folds to consts after unroll
        }
        constexpr int sc = (U + 1) % 7;   // slot completing at this plane (o = xi-6)
        if (xi >= 6 && xi < xmax) {
            if (v1) ssim_pt(acc[sc][0], acc[sc][2], acc[sc][4], acc[sc][6], acc[sc][8]);
            if (v2) ssim_pt(acc[sc][1], acc[sc][3], acc[sc][5], acc[sc][7], acc[sc][9]);
        }
        #pragma unroll
        for (int m = 0; m < 10; ++m) acc[sc][m] = 0.f;
        // No 3rd barrier: next Phase A writes zp; this plane's zp reads (Phase B)
        // are behind barrier 2. Phase C's yp reads complete before next Phase B
        // (its writes are behind next barrier 1).
    };

    loadX(0); loadY(0);
    #pragma unroll 1
    for (int b = 0; b < 28; b += 7) {
        body(b + 0, std::integral_constant<int, 0>{});
        body(b + 1, std::integral_constant<int, 1>{});
        body(b + 2, std::integral_constant<int, 2>{});
        body(b + 3, std::integral_constant<int, 3>{});
        body(b + 4, std::integral_constant<int, 4>{});
        body(b + 5, std::integral_constant<int, 5>{});
        body(b + 6, std::integral_constant<int, 6>{});
    }
    body(28, std::integral_constant<int, 0>{});
    body(29, std::integral_constant<int, 1>{});
    body(30, std::integral_constant<int, 2>{});
    body(31, std::integral_constant<int, 3>{});
    body(32, std::integral_constant<int, 4>{});

    // ---- block reduction ----
    #pragma unroll
    for (int off = 32; off > 0; off >>= 1) lsum += __shfl_down(lsum, off, 64);
    if ((tid & 63) == 0) wsum[tid >> 6] = lsum;
    __syncthreads();
    if (tid == 0)
        atomicAdd(acc_out, (double)(wsum[0] + wsum[1] + wsum[2] + wsum[3]));
}

__global__ void ssim3d_finalize(const double* __restrict__ acc, float* __restrict__ out) {
    out[0] = (float)(acc[0] / 12869712.0);   // 2 * 186^3
}

extern "C" void kernel_launch(void* const* d_in, const int* in_sizes, int n_in,
                              void* d_out, int out_size, void* d_ws, size_t ws_size,
                              hipStream_t stream) {
    (void)in_sizes; (void)n_in; (void)out_size; (void)ws_size;
    const float* x = (const float*)d_in[0];
    const float* y = (const float*)d_in[1];
    float* out = (float*)d_out;
    double* acc = (double*)d_ws;
    hipMemsetAsync(d_ws, 0, sizeof(double), stream);
    dim3 grid(3, 24, NCHX * 2);   // z-tiles, y-tiles, x-chunks*batch
    ssim3d_kernel<<<grid, 256, 0, stream>>>(x, y, acc);
    ssim3d_finalize<<<1, 1, 0, stream>>>(acc, out);
}